// Round 4
// baseline (633.751 us; speedup 1.0000x reference)
//
#include <hip/hip_runtime.h>

#define BATCH 8
#define HH 256
#define WW 256
#define BN_EPS 1e-5f

// ws float-offsets for small area
#define WS_A 128
#define WS_B 192
#define WS_COEF 256
// ws byte-offsets for big buffers
#define WA_OFF   4096ull       // 73728 B: A-frag-ready weights (bf16, 16B/lane entries)
#define PART_OFF 131072ull     // 2 x 64*8192 floats = 4 MB (sum, sumsq partials)
#define XT_OFF   4456448ull    // padded NHWC bf16 x: 8 * 258 * (258*8 blocks) * 16 B = 68.16 MB
#define Y_OFF    73400320ull   // y bf16 NCHW: 67.1 MB

typedef __attribute__((ext_vector_type(8))) short bf16x8;
typedef __attribute__((ext_vector_type(4))) float f32x4;

__device__ __forceinline__ unsigned short f2bf(float f) {
    unsigned u = __float_as_uint(f);
    u += 0x7fffu + ((u >> 16) & 1u);          // RNE
    return (unsigned short)(u >> 16);
}
__device__ __forceinline__ float bf2f(unsigned short s) {
    return __uint_as_float(((unsigned)s) << 16);
}

// x NCHW fp32 -> padded (258x258) NHWC bf16, ci in XOR-swizzled 16B blocks.
// block index within row: col*8 + (kb ^ (col&7)), kb = ci/8. One block per (b,row).
__global__ __launch_bounds__(256) void transpose_x(const float* __restrict__ in,
                                                   int4* __restrict__ xt) {
    const int row = blockIdx.x, b = blockIdx.y;
    const int tid = threadIdx.x;
    const int cg = tid & 63, kb0 = tid >> 6;
    const int base_in = (b << 22) + (row << 8);
    const int rowblk = (b * 258 + row + 1) * 2064;   // 2064 = 258 cols * 8 blocks
    for (int kb = kb0; kb < 8; kb += 4) {
        float v[8][4];
        #pragma unroll
        for (int j = 0; j < 8; ++j) {
            float4 f = *(const float4*)&in[base_in + ((kb * 8 + j) << 16) + cg * 4];
            v[j][0] = f.x; v[j][1] = f.y; v[j][2] = f.z; v[j][3] = f.w;
        }
        #pragma unroll
        for (int cc = 0; cc < 4; ++cc) {
            int col = cg * 4 + cc + 1;               // padded col
            union { short s[8]; int4 q; } u;
            #pragma unroll
            for (int j = 0; j < 8; ++j) u.s[j] = (short)f2bf(v[j][cc]);
            xt[rowblk + col * 8 + (kb ^ (col & 7))] = u.q;
        }
    }
}

// Zero the pad border of xt: rows 0/257 fully, cols 0/257 for rows 1..256. Per b: 8224 blocks.
__global__ void pad_xt(int4* __restrict__ xt) {
    int i = blockIdx.x * 256 + threadIdx.x;
    if (i >= 8 * 8224) return;
    int b = i / 8224, r = i - b * 8224;
    int blk;
    if (r < 4128) {
        int row = (r < 2064) ? 0 : 257;
        int off = (r < 2064) ? r : r - 2064;
        blk = (b * 258 + row) * 2064 + off;
    } else {
        int r2 = r - 4128;
        int row = 1 + (r2 >> 4);
        int s = r2 & 15;
        int col = (s < 8) ? 0 : 257;
        blk = (b * 258 + row) * 2064 + col * 8 + (s & 7);
    }
    xt[blk] = make_int4(0, 0, 0, 0);
}

// Weights -> A-frag-ready: entry e = f*64+lane, f = 8t+4ks+mt.
// lane holds W[co=16mt+(lane&15)][ci = ks*32 + (lane>>4)*8 + j], j=0..7, bf16.
__global__ void transpose_w(const float* __restrict__ wgt, int4* __restrict__ wA) {
    int e = blockIdx.x * 256 + threadIdx.x;
    if (e >= 4608) return;
    int le = e & 63, f = e >> 6;
    int mt = f & 3, ks = (f >> 2) & 1, t = f >> 3;
    int co = 16 * mt + (le & 15), ci0 = ks * 32 + (le >> 4) * 8;
    union { short s[8]; int4 q; } u;
    #pragma unroll
    for (int j = 0; j < 8; ++j)
        u.s[j] = (short)f2bf(wgt[(co * 64 + ci0 + j) * 9 + t]);
    wA[e] = u.q;
}

// MFMA conv: block = 4 out rows x 64 cols, all 64 co. Wave w -> out row w, tile 64co x 64px.
// acc[mt][nt]: mfma_f32_16x16x32_bf16, 9 taps x 2 ksteps. A from global (L2-hot), B from LDS.
// LDS trimmed to 66 cols (50688 B) -> 3 blocks/CU.
__global__ __launch_bounds__(256, 3) void conv_mfma(
        const int4* __restrict__ xt, const int4* __restrict__ wA,
        const float* __restrict__ bias, unsigned short* __restrict__ y,
        float* __restrict__ part) {
    __shared__ int4 xs[6 * 528];   // 6 rows x 66 cols x 8 blocks = 50688 B
    const int tid = threadIdx.x, lane = tid & 63, wv = tid >> 6;
    const int b = blockIdx.y;
    const int ht = blockIdx.x >> 2, wt = blockIdx.x & 3;
    const int h0 = ht * 4, w0 = wt * 64;
    const int bid = blockIdx.y * 256 + blockIdx.x;

    // stage 6 rows x 528 blocks (padded cols w0..w0+65; reads need LC+kw <= 65)
    for (int i = tid; i < 6 * 528; i += 256) {
        int row = i / 528, j = i - row * 528;
        xs[i] = xt[(b * 258 + h0 + row) * 2064 + w0 * 8 + j];
    }
    __syncthreads();

    const int q = lane >> 4, n = lane & 15;
    const int r = wv;
    f32x4 acc[4][4] = {};

    #pragma unroll
    for (int t = 0; t < 9; ++t) {
        const int kh = t / 3, kw = t - 3 * (t / 3);
        #pragma unroll
        for (int ks = 0; ks < 2; ++ks) {
            bf16x8 af[4];
            #pragma unroll
            for (int mt = 0; mt < 4; ++mt) {
                int4 v = wA[(8 * t + 4 * ks + mt) * 64 + lane];
                af[mt] = *(bf16x8*)&v;
            }
            bf16x8 bfr[4];
            #pragma unroll
            for (int nt = 0; nt < 4; ++nt) {
                int LC = 16 * nt + n + kw;
                int vq = (ks * 4 + q) ^ (LC & 7);
                bfr[nt] = *(const bf16x8*)&xs[(r + kh) * 528 + LC * 8 + vq];
            }
            #pragma unroll
            for (int mt = 0; mt < 4; ++mt)
                #pragma unroll
                for (int nt = 0; nt < 4; ++nt)
                    acc[mt][nt] = __builtin_amdgcn_mfma_f32_16x16x32_bf16(
                        af[mt], bfr[nt], acc[mt][nt], 0, 0, 0);
        }
    }

    // epilogue: +bias, y bf16 store, per-co row sums -> per-(block,wave) partials
    const int gr = h0 + r;
    #pragma unroll
    for (int mt = 0; mt < 4; ++mt) {
        #pragma unroll
        for (int rg = 0; rg < 4; ++rg) {
            int co = 16 * mt + 4 * q + rg;
            float bs = bias[co];
            float s1 = 0.f, s2 = 0.f;
            size_t ybase = ((size_t)(b * 64 + co) << 16) + (gr << 8) + w0 + n;
            #pragma unroll
            for (int nt = 0; nt < 4; ++nt) {
                float yv = acc[mt][nt][rg] + bs;
                y[ybase + 16 * nt] = f2bf(yv);
                s1 += yv; s2 += yv * yv;
            }
            #pragma unroll
            for (int m = 1; m < 16; m <<= 1) {
                s1 += __shfl_xor(s1, m, 64);
                s2 += __shfl_xor(s2, m, 64);
            }
            if (n == 0) {
                part[co * 8192 + bid * 4 + wv] = s1;
                part[64 * 8192 + co * 8192 + bid * 4 + wv] = s2;
            }
        }
    }
}

// blocks 0..63: reduce partials -> BN affine a,b. block 64: K = fx*fx + fy*fy (5x5), copy fx,fy.
__global__ void finalize_stats(const float* __restrict__ part,
                               const float* __restrict__ gamma, const float* __restrict__ beta,
                               const float* __restrict__ fx, const float* __restrict__ fy,
                               float* ws) {
    __shared__ float red[512];
    int t = threadIdx.x, co = blockIdx.x;
    if (co < 64) {
        float s1 = 0.f, s2 = 0.f;
        for (int i = t; i < 8192; i += 256) {
            s1 += part[co * 8192 + i];
            s2 += part[64 * 8192 + co * 8192 + i];
        }
        red[t] = s1; red[256 + t] = s2;
        __syncthreads();
        for (int st = 128; st; st >>= 1) {
            if (t < st) { red[t] += red[t + st]; red[256 + t] += red[256 + t + st]; }
            __syncthreads();
        }
        if (t == 0) {
            const float invN = 1.f / 524288.f;
            float m = red[0] * invN;
            float v = red[256] * invN - m * m;
            float a = gamma[co] * rsqrtf(v + BN_EPS);
            ws[WS_A + co] = a;
            ws[WS_B + co] = beta[co] - m * a;
        }
    } else {
        if (t < 25) {
            int c5 = t / 5, d = t % 5;
            float s = 0.f;
            for (int i = 0; i < 3; ++i)
                for (int j = 0; j < 3; ++j) {
                    int i2 = c5 - i, j2 = d - j;
                    if (i2 >= 0 && i2 < 3 && j2 >= 0 && j2 < 3)
                        s += fx[i * 3 + j] * fx[i2 * 3 + j2] + fy[i * 3 + j] * fy[i2 * 3 + j2];
                }
            ws[WS_COEF + t] = s;
        }
        if (t >= 32 && t < 41) ws[WS_COEF + 25 + (t - 32)] = fx[t - 32];
        if (t >= 48 && t < 57) ws[WS_COEF + 34 + (t - 48)] = fy[t - 48];
    }
}

// curvature: per (b,c, 64x64 tile): relu(y*a+b) staged circularly (8-aligned halo),
// then per-thread 4x4 outputs via rolling 5-row register window:
// curv = K(*)x + gx^2+gy^2-2gxgy + x.
__global__ __launch_bounds__(256, 4) void curvature2(const float* __restrict__ ws,
        const unsigned short* __restrict__ ybuf, float* __restrict__ out) {
    __shared__ float xs[72 * 84];     // rows h0-4..h0+67, cols w0-8..w0+71, stride 84
    __shared__ float cf[43];
    const int tid = threadIdx.x;
    const int c = blockIdx.y, b = blockIdx.z;
    const int h0 = (blockIdx.x >> 2) * 64, w0 = (blockIdx.x & 3) * 64;
    const float a = ws[WS_A + c], bb = ws[WS_B + c];
    const size_t ch = ((size_t)(b * 64 + c)) << 16;
    if (tid < 43) cf[tid] = ws[WS_COEF + tid];

    // stage: 72 rows x 10 int4 (8 bf16 each), vectorized + wrap-safe (8-groups aligned)
    for (int i = tid; i < 720; i += 256) {
        int rr = i / 10, g = i - rr * 10;
        int gh = (h0 - 4 + rr) & 255;
        int gw = (w0 - 8 + g * 8) & 255;
        int4 v = *(const int4*)&ybuf[ch + (gh << 8) + gw];
        const unsigned short* s = (const unsigned short*)&v;
        float o[8];
        #pragma unroll
        for (int j = 0; j < 8; ++j) o[j] = fmaxf(fmaf(bf2f(s[j]), a, bb), 0.f);
        *(float4*)&xs[rr * 84 + g * 8]     = make_float4(o[0], o[1], o[2], o[3]);
        *(float4*)&xs[rr * 84 + g * 8 + 4] = make_float4(o[4], o[5], o[6], o[7]);
    }
    __syncthreads();

    const int tx = tid & 15, ty = tid >> 4;
    const int R0 = ty * 4, C0 = tx * 4;
    // staged row s maps global h0-4+s. Output row OR uses staged rows OR..OR+4.
    // patch cols: staged C0+4 .. C0+11 (center col = cc+4).
    float p[8][8];
    #pragma unroll
    for (int j = 0; j < 5; ++j) {
        float4 u0 = *(float4*)&xs[(R0 + j) * 84 + C0 + 4];
        float4 u1 = *(float4*)&xs[(R0 + j) * 84 + C0 + 8];
        p[j][0] = u0.x; p[j][1] = u0.y; p[j][2] = u0.z; p[j][3] = u0.w;
        p[j][4] = u1.x; p[j][5] = u1.y; p[j][6] = u1.z; p[j][7] = u1.w;
    }
    #pragma unroll
    for (int rr = 0; rr < 4; ++rr) {
        if (rr) {
            float4 u0 = *(float4*)&xs[(R0 + rr + 4) * 84 + C0 + 4];
            float4 u1 = *(float4*)&xs[(R0 + rr + 4) * 84 + C0 + 8];
            p[rr + 4][0] = u0.x; p[rr + 4][1] = u0.y; p[rr + 4][2] = u0.z; p[rr + 4][3] = u0.w;
            p[rr + 4][4] = u1.x; p[rr + 4][5] = u1.y; p[rr + 4][6] = u1.z; p[rr + 4][7] = u1.w;
        }
        float res[4];
        #pragma unroll
        for (int cc = 0; cc < 4; ++cc) {
            float gx = 0.f, gy = 0.f, kc = 0.f;
            #pragma unroll
            for (int a2 = 0; a2 < 3; ++a2)
                #pragma unroll
                for (int b2 = 0; b2 < 3; ++b2) {
                    float xv = p[rr + 4 - a2][cc + 4 - b2];
                    gx = fmaf(cf[25 + a2 * 3 + b2], xv, gx);
                    gy = fmaf(cf[34 + a2 * 3 + b2], xv, gy);
                }
            #pragma unroll
            for (int c5 = 0; c5 < 5; ++c5)
                #pragma unroll
                for (int d = 0; d < 5; ++d)
                    kc = fmaf(cf[c5 * 5 + d], p[rr + 4 - c5][cc + 4 - d], kc);
            res[cc] = kc + gx * gx + gy * gy - 2.f * gx * gy + p[rr + 4][cc + 4];
        }
        f32x4 rv = { res[0], res[1], res[2], res[3] };
        __builtin_nontemporal_store(rv,
            (f32x4*)&out[ch + ((size_t)(h0 + R0 + rr) << 8) + w0 + C0]);
    }
}

extern "C" void kernel_launch(void* const* d_in, const int* in_sizes, int n_in,
                              void* d_out, int out_size, void* d_ws, size_t ws_size,
                              hipStream_t stream) {
    const float* in    = (const float*)d_in[0];
    const float* wgt   = (const float*)d_in[1];
    const float* bias  = (const float*)d_in[2];
    const float* gamma = (const float*)d_in[3];
    const float* beta  = (const float*)d_in[4];
    const float* fx    = (const float*)d_in[5];
    const float* fy    = (const float*)d_in[6];
    float* out = (float*)d_out;

    float* wsf = (float*)d_ws;
    int4*  wA   = (int4*)((char*)d_ws + WA_OFF);
    float* part = (float*)((char*)d_ws + PART_OFF);
    int4*  xt   = (int4*)((char*)d_ws + XT_OFF);
    unsigned short* ybuf = (unsigned short*)((char*)d_ws + Y_OFF);

    hipLaunchKernelGGL(transpose_x, dim3(256, 8), dim3(256), 0, stream, in, xt);
    hipLaunchKernelGGL(pad_xt, dim3(257), dim3(256), 0, stream, xt);
    hipLaunchKernelGGL(transpose_w, dim3(18), dim3(256), 0, stream, wgt, wA);
    hipLaunchKernelGGL(conv_mfma, dim3(256, 8), dim3(256), 0, stream,
                       xt, wA, bias, ybuf, part);
    hipLaunchKernelGGL(finalize_stats, dim3(65), dim3(256), 0, stream,
                       part, gamma, beta, fx, fy, wsf);
    hipLaunchKernelGGL(curvature2, dim3(16, 64, 8), dim3(256), 0, stream,
                       wsf, ybuf, out);
}